// Round 2
// baseline (99.462 us; speedup 1.0000x reference)
//
#include <hip/hip_runtime.h>

// 4x4-pixel tiles per thread. Tiles-per-dim per scale:
#define G1 64   // H=W=256: interior 254 -> 64 tiles (last tile 2 rows/cols)
#define G2 32   // 128: interior 126
#define G3 16   // 64:  interior 62
#define TT1 (G1*G1)          // 4096 -> blocks 0..15
#define TT2 (G2*G2)          // 1024 -> blocks 16..19
#define TT3 (G3*G3)          // 256  -> block 20
#define TTOT (TT1+TT2+TT3)   // 5376 = 21 blocks * 256
#define NBLK 21
#define NBATCH 64
#define NPART (NBLK*NBATCH)  // 1344 partial-slots, 8 ints each
#define MAGIC 0xA5C3F00D     // pair-validation key (poison-proof handshake)

template<int W>
__device__ __forceinline__ void load_row(const float* __restrict__ h, int r,
                                         int j0, bool fullj, float a[8]) {
    const float* p = h + r * W + (j0 - 1);   // j0-1 = 4*tx -> 16B aligned
    float4 lo = *(const float4*)p;
    a[0] = lo.x; a[1] = lo.y; a[2] = lo.z; a[3] = lo.w;
    float4 hi = make_float4(0.f, 0.f, 0.f, 0.f);
    if (fullj) hi = *(const float4*)(p + 4);
    a[4] = hi.x; a[5] = hi.y; a[6] = hi.z; a[7] = hi.w;
}

template<int W, int R>
__device__ __forceinline__ void do_tile(const float* __restrict__ h,
                                        int ty, int tx,
                                        int& sy, int& sx, int& cnt) {
    const int i0 = 1 + 4 * ty;
    const int j0 = 1 + 4 * tx;
    const int ilast = min(i0 + 3, W - 2);      // last tile row: only 2 valid rows
    const bool fullj = (j0 + 3 <= W - 2);      // last strip: only 2 valid cols

    float a[3][8];
    load_row<W>(h, i0 - 1, j0, fullj, a[0]);
    load_row<W>(h, i0,     j0, fullj, a[1]);

    #pragma unroll
    for (int k = 0; k < 4; k++) {
        const int i = i0 + k;
        if (i <= ilast) {
            load_row<W>(h, i + 1, j0, fullj, a[(k + 2) % 3]);
            const float* top = a[k % 3];
            const float* mid = a[(k + 1) % 3];
            const float* bot = a[(k + 2) % 3];
            #pragma unroll
            for (int p = 0; p < 4; p++) {
                const float c = mid[p + 1];
                // strict peak <=> c > max(8 neighbors); bit-identical for
                // non-NaN input. Nested fmaxf fuses to v_max3_f32.
                const float ht = fmaxf(fmaxf(top[p], top[p + 1]), top[p + 2]);
                const float hb = fmaxf(fmaxf(bot[p], bot[p + 1]), bot[p + 2]);
                const float gm = fmaxf(mid[p], mid[p + 2]);
                const float nmax = fmaxf(fmaxf(ht, hb), gm);
                if ((c > nmax) && (j0 + p <= W - 2)) {
                    sy += R * i; sx += R * (j0 + p); cnt++;
                }
            }
        }
    }
}

__device__ __forceinline__ int wave_reduce_i(int v) {
    #pragma unroll
    for (int o = 32; o > 0; o >>= 1) v += __shfl_down(v, o, 64);
    return v;
}

__device__ __forceinline__ void ws_put(int* __restrict__ ws, int idx, int v) {
    __hip_atomic_store(&ws[idx],     v,         __ATOMIC_RELAXED, __HIP_MEMORY_SCOPE_AGENT);
    __hip_atomic_store(&ws[idx + 1], v ^ MAGIC, __ATOMIC_RELAXED, __HIP_MEMORY_SCOPE_AGENT);
}

// Single fused kernel. All 1344 blocks produce per-block partials into ws
// (each value stored as a self-validating {v, v^MAGIC} pair, agent scope —
// poison fill is a uniform word pattern so poisoned pairs XOR to 0, never
// MAGIC). Block (bx=20, n=63) then acts as the finalizer: it polls the pairs
// until all are valid and computes the loss — no second dispatch, no grid
// sync, no zero-init requirement. Producers never wait on anything, so the
// spin cannot deadlock.
__global__ __launch_bounds__(256) void fused_kernel(
    const float* __restrict__ p1, const float* __restrict__ p2,
    const float* __restrict__ p3, const float* __restrict__ target,
    int* __restrict__ ws, float* __restrict__ out) {
    const int n   = blockIdx.y;
    const int bx  = blockIdx.x;
    const int pid = bx * 256 + threadIdx.x;   // < 5376 exactly

    int sy = 0, sx = 0, c = 0;
    if (pid < TT1) {                                   // blocks 0..15 (wave-uniform)
        do_tile<256, 4>(p1 + n * 196608 + 131072, pid >> 6, pid & 63, sy, sx, c);
    } else if (pid < TT1 + TT2) {                      // blocks 16..19
        const int q = pid - TT1;
        do_tile<128, 8>(p2 + n * 49152 + 32768, q >> 5, q & 31, sy, sx, c);
    } else {                                           // block 20
        const int q = pid - (TT1 + TT2);
        do_tile<64, 16>(p3 + n * 12288 + 8192, q >> 4, q & 15, sy, sx, c);
    }

    sy = wave_reduce_i(sy);
    sx = wave_reduce_i(sx);
    c  = wave_reduce_i(c);

    __shared__ int smem[3][4];
    const int lane = threadIdx.x & 63, wid = threadIdx.x >> 6;
    if (lane == 0) { smem[0][wid] = sy; smem[1][wid] = sx; smem[2][wid] = c; }
    __syncthreads();
    if (threadIdx.x == 0) {
        const int base = (n * NBLK + bx) * 8;
        ws_put(ws, base + 0, smem[0][0] + smem[0][1] + smem[0][2] + smem[0][3]);
        ws_put(ws, base + 2, smem[1][0] + smem[1][1] + smem[1][2] + smem[1][3]);
        ws_put(ws, base + 4, smem[2][0] + smem[2][1] + smem[2][2] + smem[2][3]);
    }

    // ---- finalizer block only ----
    if (!(bx == NBLK - 1 && n == NBATCH - 1)) return;
    __threadfence();   // keep own stores ordered before the polls

    const int t  = threadIdx.x;
    const int bn = t >> 2;     // batch 0..63
    const int s  = t & 3;      // sub-slice 0..3

    int isy = 0, isx = 0, cnt = 0;
    for (int m = 0; m < 6; m++) {
        const int b = s + 4 * m;
        if (b < NBLK) {
            const int base = (bn * NBLK + b) * 8;
            int vy, vx, vc;
            while (true) {
                vy = __hip_atomic_load(&ws[base + 0], __ATOMIC_RELAXED, __HIP_MEMORY_SCOPE_AGENT);
                int ky = __hip_atomic_load(&ws[base + 1], __ATOMIC_RELAXED, __HIP_MEMORY_SCOPE_AGENT);
                vx = __hip_atomic_load(&ws[base + 2], __ATOMIC_RELAXED, __HIP_MEMORY_SCOPE_AGENT);
                int kx = __hip_atomic_load(&ws[base + 3], __ATOMIC_RELAXED, __HIP_MEMORY_SCOPE_AGENT);
                vc = __hip_atomic_load(&ws[base + 4], __ATOMIC_RELAXED, __HIP_MEMORY_SCOPE_AGENT);
                int kc = __hip_atomic_load(&ws[base + 5], __ATOMIC_RELAXED, __HIP_MEMORY_SCOPE_AGENT);
                if (((vy ^ ky) == MAGIC) & ((vx ^ kx) == MAGIC) & ((vc ^ kc) == MAGIC)) break;
            }
            isy += vy; isx += vx; cnt += vc;
        }
    }

    float ty = 0.f, tx = 0.f;
    const float* tp = target + bn * 160 + s * 5;
    #pragma unroll
    for (int m = 0; m < 8; m++) {               // boxes k = s + 4*m
        const float* q = tp + m * 20;
        ty += (q[2] + q[0]) * 0.5f;
        tx += (q[3] + q[1]) * 0.5f;
    }

    // Reduce the 4 sub-slices of each batch (groups of 4 consecutive lanes).
    isy += __shfl_down(isy, 2, 4); isy += __shfl_down(isy, 1, 4);
    isx += __shfl_down(isx, 2, 4); isx += __shfl_down(isx, 1, 4);
    cnt += __shfl_down(cnt, 2, 4); cnt += __shfl_down(cnt, 1, 4);
    ty  += __shfl_down(ty,  2, 4); ty  += __shfl_down(ty,  1, 4);
    tx  += __shfl_down(tx,  2, 4); tx  += __shfl_down(tx,  1, 4);

    double offx = 0.0, offy = 0.0, cy_t = 0.0, cx_t = 0.0,
           ty_t = 0.0, tx_t = 0.0, pcnt = 0.0;
    if (s == 0) {   // this lane now holds batch bn's full per-batch sums
        const float csy = (float)isy;
        const float csx = (float)isx;
        const float dy = fabsf(csy - ty);
        const float dx = fabsf(csx - tx);
        offx = (dy < 1.f) ? 0.5 * (double)dy * dy : (double)dy - 0.5;
        offy = (dx < 1.f) ? 0.5 * (double)dx * dx : (double)dx - 0.5;
        cy_t = csy; cx_t = csx; ty_t = ty; tx_t = tx; pcnt = cnt;
    }

    #pragma unroll
    for (int o = 32; o > 0; o >>= 1) {
        offx += __shfl_down(offx, o, 64);
        offy += __shfl_down(offy, o, 64);
        cy_t += __shfl_down(cy_t, o, 64);
        cx_t += __shfl_down(cx_t, o, 64);
        ty_t += __shfl_down(ty_t, o, 64);
        tx_t += __shfl_down(tx_t, o, 64);
        pcnt += __shfl_down(pcnt, o, 64);
    }

    __shared__ double fsm[4][7];
    if ((t & 63) == 0) {
        const int w = t >> 6;
        fsm[w][0] = offx; fsm[w][1] = offy; fsm[w][2] = cy_t;
        fsm[w][3] = cx_t; fsm[w][4] = ty_t; fsm[w][5] = tx_t;
        fsm[w][6] = pcnt;
    }
    __syncthreads();
    if (t == 0) {
        double OX = 0, OY = 0, CY = 0, CX = 0, TY = 0, TX = 0, PC = 0;
        #pragma unroll
        for (int w = 0; w < 4; w++) {
            OX += fsm[w][0]; OY += fsm[w][1]; CY += fsm[w][2];
            CX += fsm[w][3]; TY += fsm[w][4]; TX += fsm[w][5]; PC += fsm[w][6];
        }
        const double sgnx = OX / fabs(OX);
        const double sgny = OY / fabs(OY);
        out[0] = (float)((sgnx * (CY - TY) + sgny * (CX - TX)) / PC);
    }
}

extern "C" void kernel_launch(void* const* d_in, const int* in_sizes, int n_in,
                              void* d_out, int out_size, void* d_ws, size_t ws_size,
                              hipStream_t stream) {
    const float* p1     = (const float*)d_in[0];
    const float* p2     = (const float*)d_in[1];
    const float* p3     = (const float*)d_in[2];
    const float* target = (const float*)d_in[3];
    float* out = (float*)d_out;
    int*   ws  = (int*)d_ws;

    dim3 grid(NBLK, NBATCH);   // 21 x 64 blocks, single fused dispatch
    fused_kernel<<<grid, 256, 0, stream>>>(p1, p2, p3, target, ws, out);
}

// Round 3
// 97.849 us; speedup vs baseline: 1.0165x; 1.0165x over previous
//
#include <hip/hip_runtime.h>

// 4x4-pixel tiles per thread. Tiles-per-dim per scale:
#define G1 64   // H=W=256: interior 254 -> 64 tiles (last tile 2 rows/cols)
#define G2 32   // 128: interior 126
#define G3 16   // 64:  interior 62
#define TT1 (G1*G1)          // 4096 -> blocks 0..15
#define TT2 (G2*G2)          // 1024 -> blocks 16..19
#define TT3 (G3*G3)          // 256  -> block 20
#define TTOT (TT1+TT2+TT3)   // 5376 = 21 blocks * 256
#define NBLK 21
#define NBATCH 64
#define NPART (NBLK*NBATCH)  // 1344 partials per component

template<int W>
__device__ __forceinline__ void load_row(const float* __restrict__ h, int r,
                                         int j0, bool fullj, float a[8]) {
    const float* p = h + r * W + (j0 - 1);   // j0-1 = 4*tx -> 16B aligned
    float4 lo = *(const float4*)p;
    a[0] = lo.x; a[1] = lo.y; a[2] = lo.z; a[3] = lo.w;
    float4 hi = make_float4(0.f, 0.f, 0.f, 0.f);
    if (fullj) hi = *(const float4*)(p + 4);
    a[4] = hi.x; a[5] = hi.y; a[6] = hi.z; a[7] = hi.w;
}

template<int W, int R>
__device__ __forceinline__ void do_tile(const float* __restrict__ h,
                                        int ty, int tx,
                                        int& sy, int& sx, int& cnt) {
    const int i0 = 1 + 4 * ty;
    const int j0 = 1 + 4 * tx;
    const int ilast = min(i0 + 3, W - 2);      // last tile row: only 2 valid rows
    const bool fullj = (j0 + 3 <= W - 2);      // last strip: only 2 valid cols

    float a[3][8];
    load_row<W>(h, i0 - 1, j0, fullj, a[0]);
    load_row<W>(h, i0,     j0, fullj, a[1]);

    #pragma unroll
    for (int k = 0; k < 4; k++) {
        const int i = i0 + k;
        if (i <= ilast) {
            load_row<W>(h, i + 1, j0, fullj, a[(k + 2) % 3]);
            const float* top = a[k % 3];
            const float* mid = a[(k + 1) % 3];
            const float* bot = a[(k + 2) % 3];
            #pragma unroll
            for (int p = 0; p < 4; p++) {
                const float c = mid[p + 1];
                // strict peak <=> c > max(8 neighbors); bit-identical for
                // non-NaN input. Nested fmaxf fuses to v_max3_f32.
                const float ht = fmaxf(fmaxf(top[p], top[p + 1]), top[p + 2]);
                const float hb = fmaxf(fmaxf(bot[p], bot[p + 1]), bot[p + 2]);
                const float gm = fmaxf(mid[p], mid[p + 2]);
                const float nmax = fmaxf(fmaxf(ht, hb), gm);
                if ((c > nmax) && (j0 + p <= W - 2)) {
                    sy += R * i; sx += R * (j0 + p); cnt++;
                }
            }
        }
    }
}

__device__ __forceinline__ int wave_reduce_i(int v) {
    #pragma unroll
    for (int o = 32; o > 0; o >>= 1) v += __shfl_down(v, o, 64);
    return v;
}

__global__ __launch_bounds__(256) void peaks_kernel(
    const float* __restrict__ p1, const float* __restrict__ p2,
    const float* __restrict__ p3, int* __restrict__ ws) {
    const int n   = blockIdx.y;
    const int bx  = blockIdx.x;
    const int pid = bx * 256 + threadIdx.x;   // < 5376 exactly

    int sy = 0, sx = 0, c = 0;
    if (pid < TT1) {                                   // blocks 0..15 (wave-uniform)
        do_tile<256, 4>(p1 + n * 196608 + 131072, pid >> 6, pid & 63, sy, sx, c);
    } else if (pid < TT1 + TT2) {                      // blocks 16..19
        const int q = pid - TT1;
        do_tile<128, 8>(p2 + n * 49152 + 32768, q >> 5, q & 31, sy, sx, c);
    } else {                                           // block 20
        const int q = pid - (TT1 + TT2);
        do_tile<64, 16>(p3 + n * 12288 + 8192, q >> 4, q & 15, sy, sx, c);
    }

    sy = wave_reduce_i(sy);
    sx = wave_reduce_i(sx);
    c  = wave_reduce_i(c);

    __shared__ int smem[3][4];
    const int lane = threadIdx.x & 63, wid = threadIdx.x >> 6;
    if (lane == 0) { smem[0][wid] = sy; smem[1][wid] = sx; smem[2][wid] = c; }
    __syncthreads();
    if (threadIdx.x == 0) {
        // Per-block partial write — no zero-init of ws required (poison-proof).
        const int slot = n * NBLK + bx;
        ws[slot]             = smem[0][0] + smem[0][1] + smem[0][2] + smem[0][3];
        ws[NPART + slot]     = smem[1][0] + smem[1][1] + smem[1][2] + smem[1][3];
        ws[2 * NPART + slot] = smem[2][0] + smem[2][1] + smem[2][2] + smem[2][3];
    }
}

// 256 threads: 4 lanes per batch (bn = tid>>2, s = tid&3). Each lane covers
// 1/4 of the 21 ws slots and 1/4 of the 32 target boxes -> 4x fewer serial
// load issues per lane and 4 waves of latency hiding vs a single wave.
__global__ __launch_bounds__(256) void finalize_kernel(
    const int* __restrict__ ws, const float* __restrict__ target,
    float* __restrict__ out) {
    const int t  = threadIdx.x;
    const int bn = t >> 2;     // batch 0..63
    const int s  = t & 3;      // sub-slice 0..3

    int isy = 0, isx = 0, cnt = 0;
    #pragma unroll
    for (int m = 0; m < 6; m++) {
        const int b = s + 4 * m;
        if (b < NBLK) {
            const int slot = bn * NBLK + b;
            isy += ws[slot];
            isx += ws[NPART + slot];
            cnt += ws[2 * NPART + slot];
        }
    }

    float ty = 0.f, tx = 0.f;
    const float* tp = target + bn * 160 + s * 5;
    #pragma unroll
    for (int m = 0; m < 8; m++) {               // boxes k = s + 4*m
        const float* q = tp + m * 20;
        ty += (q[2] + q[0]) * 0.5f;
        tx += (q[3] + q[1]) * 0.5f;
    }

    // Reduce the 4 sub-slices of each batch (groups of 4 consecutive lanes).
    isy += __shfl_down(isy, 2, 4); isy += __shfl_down(isy, 1, 4);
    isx += __shfl_down(isx, 2, 4); isx += __shfl_down(isx, 1, 4);
    cnt += __shfl_down(cnt, 2, 4); cnt += __shfl_down(cnt, 1, 4);
    ty  += __shfl_down(ty,  2, 4); ty  += __shfl_down(ty,  1, 4);
    tx  += __shfl_down(tx,  2, 4); tx  += __shfl_down(tx,  1, 4);

    double offx = 0.0, offy = 0.0, cy_t = 0.0, cx_t = 0.0,
           ty_t = 0.0, tx_t = 0.0, pcnt = 0.0;
    if (s == 0) {   // this lane now holds batch bn's full per-batch sums
        const float csy = (float)isy;
        const float csx = (float)isx;
        const float dy = fabsf(csy - ty);
        const float dx = fabsf(csx - tx);
        offx = (dy < 1.f) ? 0.5 * (double)dy * dy : (double)dy - 0.5;
        offy = (dx < 1.f) ? 0.5 * (double)dx * dx : (double)dx - 0.5;
        cy_t = csy; cx_t = csx; ty_t = ty; tx_t = tx; pcnt = cnt;
    }

    #pragma unroll
    for (int o = 32; o > 0; o >>= 1) {
        offx += __shfl_down(offx, o, 64);
        offy += __shfl_down(offy, o, 64);
        cy_t += __shfl_down(cy_t, o, 64);
        cx_t += __shfl_down(cx_t, o, 64);
        ty_t += __shfl_down(ty_t, o, 64);
        tx_t += __shfl_down(tx_t, o, 64);
        pcnt += __shfl_down(pcnt, o, 64);
    }

    __shared__ double fsm[4][7];
    const int lane = t & 63, wid = t >> 6;
    if (lane == 0) {
        fsm[wid][0] = offx; fsm[wid][1] = offy; fsm[wid][2] = cy_t;
        fsm[wid][3] = cx_t; fsm[wid][4] = ty_t; fsm[wid][5] = tx_t;
        fsm[wid][6] = pcnt;
    }
    __syncthreads();
    if (t == 0) {
        double OX = 0, OY = 0, CY = 0, CX = 0, TY = 0, TX = 0, PC = 0;
        #pragma unroll
        for (int w = 0; w < 4; w++) {
            OX += fsm[w][0]; OY += fsm[w][1]; CY += fsm[w][2];
            CX += fsm[w][3]; TY += fsm[w][4]; TX += fsm[w][5]; PC += fsm[w][6];
        }
        const double sgnx = OX / fabs(OX);
        const double sgny = OY / fabs(OY);
        out[0] = (float)((sgnx * (CY - TY) + sgny * (CX - TX)) / PC);
    }
}

extern "C" void kernel_launch(void* const* d_in, const int* in_sizes, int n_in,
                              void* d_out, int out_size, void* d_ws, size_t ws_size,
                              hipStream_t stream) {
    const float* p1     = (const float*)d_in[0];
    const float* p2     = (const float*)d_in[1];
    const float* p3     = (const float*)d_in[2];
    const float* target = (const float*)d_in[3];
    float* out = (float*)d_out;
    int*   ws  = (int*)d_ws;

    dim3 grid(NBLK, NBATCH);   // 21 x 64 blocks
    peaks_kernel<<<grid, 256, 0, stream>>>(p1, p2, p3, ws);
    finalize_kernel<<<1, 256, 0, stream>>>(ws, target, out);
}